// Round 5
// baseline (205.369 us; speedup 1.0000x reference)
//
#include <hip/hip_runtime.h>
#include <hip/hip_fp16.h>

#define Bn   4
#define CINc 64
#define COUTc 64
#define Hn   128
#define Wn   128
#define HW   (Hn * Wn)
#define KKc  9
#define NOFF 18

typedef short bf16x8 __attribute__((ext_vector_type(8)));
typedef float f32x4  __attribute__((ext_vector_type(4)));

__device__ inline unsigned short f2bf(float f) {   // RNE fp32 -> bf16
    unsigned int u = __float_as_uint(f);
    return (unsigned short)((u + 0x7fffu + ((u >> 16) & 1u)) >> 16);
}

// ---------------------------------------------------------------------------
// prep: wkb[k][o][c] bf16 <- w_def[o][c][k] ; wob[t][m(32,pad)][c] bf16 <- w_off
// ---------------------------------------------------------------------------
__global__ void prep_weights(const float* __restrict__ w_off,
                             const float* __restrict__ w_def,
                             unsigned short* __restrict__ wkb,
                             unsigned short* __restrict__ wob) {
    int idx = blockIdx.x * 256 + threadIdx.x;
    if (idx < COUTc * CINc * KKc) {                 // 36864
        int k = idx % 9;
        int c = (idx / 9) % 64;
        int o = idx / 576;
        wkb[((size_t)k * 64 + o) * 64 + c] = f2bf(w_def[idx]);
    }
    int j = idx - COUTc * CINc * KKc;
    if (j >= 0 && j < KKc * 32 * CINc) {            // 18432: wob[t<<11|m<<6|c]
        int c = j & 63, m = (j >> 6) & 31, t = j >> 11;
        unsigned short v = 0;
        if (m < NOFF) v = f2bf(w_off[((size_t)m * 64 + c) * 9 + t]);
        wob[j] = v;
    }
}

// ---------------------------------------------------------------------------
// Fully fused deformable conv. Block = (b, h, 64-px half), 1024 blocks,
// 256 thr, XCD-swizzled h. Per-wave p-strip decomposition: wave w owns
// pixels w*16..w*16+15; lane (l15,quad) owns pixel l15, channels
// {kc*32+quad*8+j} — exactly its MFMA B-frag slots, so bilinear blends go
// straight into MFMA registers (no LDS round-trip, no per-k barriers).
// Stages: [x window -> LDS] B1 [offset-conv MFMA -> s_off] B2
// [phase-1 addr/wt -> LDS] B3 [9x barrier-free gather+blend+MFMA] [store].
// ---------------------------------------------------------------------------
__global__ __launch_bounds__(256, 4) void fused_deform(
        const float* __restrict__ x, const unsigned short* __restrict__ wob,
        const unsigned short* __restrict__ wkb, const float* __restrict__ b_off,
        float* __restrict__ out) {
    __shared__ unsigned s_xw[32][3][68];   // [c-pair][row][col] bf16x2, 26.1 KB
    __shared__ float    s_off[4][NOFF][16];// per-wave off values, 4.6 KB
    __shared__ unsigned s_ad[KKc][64];     // packed yc0 | yc1<<8 | xc<<16
    __shared__ __half2  s_wh[KKc][64][2];  // folded corner weights (fp16)

    int gid  = blockIdx.x;                 // 1024
    int xcd  = gid & 7;
    int j    = gid >> 3;
    int half = j & 1;
    int hh   = (j >> 1) & 15;
    int b    = (j >> 5) & 3;
    int h    = xcd * 16 + hh;
    int w0   = half * 64;
    int tid  = threadIdx.x;
    int lane = tid & 63;
    int wave = __builtin_amdgcn_readfirstlane(tid >> 6);
    int l15  = lane & 15;
    int quad = lane >> 4;

    const float* xb = x + (size_t)b * CINc * HW;

    // ---- stage x window: rows h-1..h+1, cols w0-2..w0+65, 64 ch bf16 ----
    #pragma unroll
    for (int i = 0; i < 26; ++i) {
        int idx = tid + i * 256;           // 32*3*68 = 6528 dwords
        if (idx < 6528) {
            int cp  = idx / 204;
            int rem = idx - cp * 204;
            int r   = rem / 68;
            int col = rem - r * 68;
            int y   = h - 1 + r;
            int xg  = w0 - 2 + col;
            unsigned v = 0;
            if (y >= 0 && y < Hn && xg >= 0 && xg < Wn) {
                const float* p0 = xb + (size_t)(2 * cp) * HW + y * Wn + xg;
                v = (unsigned)f2bf(p0[0]) | ((unsigned)f2bf(p0[HW]) << 16);
            }
            s_xw[cp][r][col] = v;
        }
    }
    __syncthreads();

    // ---- offset conv: 9-tap MFMA GEMM, M=32(18 used) x N=16(p-strip) ----
    f32x4 oa0 = (f32x4){0.f, 0.f, 0.f, 0.f};
    f32x4 oa1 = (f32x4){0.f, 0.f, 0.f, 0.f};
    #pragma unroll
    for (int t = 0; t < 9; ++t) {
        int ty = t / 3, tx = t % 3;
        int colw = wave * 16 + l15 + 1 + tx;       // window col of pixel tap
        #pragma unroll
        for (int kc = 0; kc < 2; ++kc) {
            union { bf16x8 v; unsigned u[4]; } bf;
            #pragma unroll
            for (int i = 0; i < 4; ++i)
                bf.u[i] = s_xw[kc * 16 + quad * 4 + i][ty][colw];
            bf16x8 a0 = *(const bf16x8*)(wob + ((t * 32 + l15) * 64 + kc * 32 + quad * 8));
            bf16x8 a1 = *(const bf16x8*)(wob + ((t * 32 + 16 + l15) * 64 + kc * 32 + quad * 8));
            oa0 = __builtin_amdgcn_mfma_f32_16x16x32_bf16(a0, bf.v, oa0, 0, 0, 0);
            oa1 = __builtin_amdgcn_mfma_f32_16x16x32_bf16(a1, bf.v, oa1, 0, 0, 0);
        }
    }
    #pragma unroll
    for (int r = 0; r < 4; ++r)
        s_off[wave][quad * 4 + r][l15] = oa0[r] + b_off[quad * 4 + r];
    if (quad == 0) {
        s_off[wave][16][l15] = oa1[0] + b_off[16];
        s_off[wave][17][l15] = oa1[1] + b_off[17];
    }
    __syncthreads();

    // ---- phase 1: fold bilinear clipping into 4 weights + packed addrs ----
    for (int jj = lane; jj < 144; jj += 64) {
        int k = jj >> 4, pl = jj & 15;
        float dy = s_off[wave][2 * k][pl];
        float dx = s_off[wave][2 * k + 1][pl];
        int pgl = w0 + wave * 16 + pl;
        float py = (float)(h - 1 + k / 3) + dy;
        float px = (float)(pgl - 1 + k % 3) + dx;
        float y0f = floorf(py), x0f = floorf(px);
        float fy = py - y0f, fx = px - x0f;
        int y0 = (int)y0f, x0 = (int)x0f;
        bool vy0 = (y0 >= 0) & (y0 < Hn);
        bool vy1 = (y0 + 1 >= 0) & (y0 + 1 < Hn);
        bool vx0 = (x0 >= 0) & (x0 < Wn);
        bool vx1 = (x0 + 1 >= 0) & (x0 + 1 < Wn);
        float wy0 = vy0 ? 1.f - fy : 0.f;
        float wy1 = vy1 ? fy : 0.f;
        float wx0 = vx0 ? 1.f - fx : 0.f;
        float wx1 = vx1 ? fx : 0.f;
        int xc = min(max(x0, 0), Wn - 2);
        bool sel0 = (min(max(x0, 0), Wn - 1) != xc);
        bool sel1 = ((min(max(x0 + 1, 0), Wn - 1) - xc) == 1);
        float Wa = (sel0 ? 0.f : wx0) + (sel1 ? 0.f : wx1);
        float Wb = (sel0 ? wx0 : 0.f) + (sel1 ? wx1 : 0.f);
        int yc0 = min(max(y0, 0), Hn - 1), yc1 = min(max(y0 + 1, 0), Hn - 1);
        int pi = wave * 16 + pl;
        s_ad[k][pi] = (unsigned)yc0 | ((unsigned)yc1 << 8) | ((unsigned)xc << 16);
        s_wh[k][pi][0] = __floats2half2_rn(wy0 * Wa, wy0 * Wb);
        s_wh[k][pi][1] = __floats2half2_rn(wy1 * Wa, wy1 * Wb);
    }
    __syncthreads();

    // ---- main loop: barrier-free gather -> in-register B-frag -> MFMA ----
    f32x4 acc[4];
    #pragma unroll
    for (int ot = 0; ot < 4; ++ot) acc[ot] = (f32x4){0.f, 0.f, 0.f, 0.f};

    for (int k = 0; k < KKc; ++k) {
        int pi = wave * 16 + l15;
        unsigned ad = s_ad[k][pi];
        int xc   = (int)(ad >> 16);
        int atop = (int)(ad & 255) * Wn + xc;
        int abot = (int)((ad >> 8) & 255) * Wn + xc;
        __half2 w01 = s_wh[k][pi][0], w23 = s_wh[k][pi][1];
        float W0 = __low2float(w01), W1 = __high2float(w01);
        float W2 = __low2float(w23), W3 = __high2float(w23);

        bf16x8 af[4][2];                   // A-frags: all 4 o-tiles (L1-hot)
        #pragma unroll
        for (int ot = 0; ot < 4; ++ot)
            #pragma unroll
            for (int kc = 0; kc < 2; ++kc)
                af[ot][kc] = *(const bf16x8*)(wkb +
                    (((size_t)k * 64 + ot * 16 + l15) * 64 + kc * 32 + quad * 8));

        #pragma unroll
        for (int kc = 0; kc < 2; ++kc) {
            union { bf16x8 v; unsigned u[4]; } bf;
            #pragma unroll
            for (int i = 0; i < 4; ++i) {
                int c0 = kc * 32 + quad * 8 + 2 * i;
                const float* p0 = xb + (size_t)c0 * HW;
                const float* p1 = p0 + HW;
                float2 t0 = *(const float2*)(p0 + atop);
                float2 b0 = *(const float2*)(p0 + abot);
                float2 t1 = *(const float2*)(p1 + atop);
                float2 b1 = *(const float2*)(p1 + abot);
                float v0 = W0 * t0.x + W1 * t0.y + W2 * b0.x + W3 * b0.y;
                float v1 = W0 * t1.x + W1 * t1.y + W2 * b1.x + W3 * b1.y;
                bf.u[i] = (unsigned)f2bf(v0) | ((unsigned)f2bf(v1) << 16);
            }
            #pragma unroll
            for (int ot = 0; ot < 4; ++ot)
                acc[ot] = __builtin_amdgcn_mfma_f32_16x16x32_bf16(af[ot][kc], bf.v, acc[ot], 0, 0, 0);
        }
    }

    // ---- epilogue: C layout col=l15 (=pixel), row=quad*4+r (=o in tile) ----
    #pragma unroll
    for (int ot = 0; ot < 4; ++ot)
        #pragma unroll
        for (int r = 0; r < 4; ++r) {
            int o = ot * 16 + quad * 4 + r;
            int p = w0 + wave * 16 + l15;
            out[(((size_t)b * COUTc + o) * Hn + h) * Wn + p] = acc[ot][r];
        }
}

// ---------------------------------------------------------------------------
extern "C" void kernel_launch(void* const* d_in, const int* in_sizes, int n_in,
                              void* d_out, int out_size, void* d_ws, size_t ws_size,
                              hipStream_t stream) {
    const float* x     = (const float*)d_in[0];
    const float* w_off = (const float*)d_in[1];
    const float* b_off = (const float*)d_in[2];
    const float* w_def = (const float*)d_in[3];
    float* out = (float*)d_out;

    char* ws = (char*)d_ws;
    unsigned short* wkb = (unsigned short*)ws;                // 73728 B
    ws += (size_t)KKc * COUTc * CINc * sizeof(unsigned short);
    unsigned short* wob = (unsigned short*)ws;                // 36864 B

    prep_weights<<<216, 256, 0, stream>>>(w_off, w_def, wkb, wob);
    fused_deform<<<Bn * Hn * (Wn / 64), 256, 0, stream>>>(x, wob, wkb, b_off, out);
}

// Round 6
// 165.564 us; speedup vs baseline: 1.2404x; 1.2404x over previous
//
#include <hip/hip_runtime.h>
#include <hip/hip_fp16.h>

#define Bn   4
#define CINc 64
#define COUTc 64
#define Hn   128
#define Wn   128
#define HW   (Hn * Wn)
#define KKc  9
#define NOFF 18

typedef short bf16x8 __attribute__((ext_vector_type(8)));
typedef float f32x4  __attribute__((ext_vector_type(4)));

__device__ inline unsigned short f2bf(float f) {   // RNE fp32 -> bf16
    unsigned int u = __float_as_uint(f);
    return (unsigned short)((u + 0x7fffu + ((u >> 16) & 1u)) >> 16);
}

// ---------------------------------------------------------------------------
// transpose_x: x[b][c][h][w] f32  ->  xt[b][h][w][c] bf16  (channel-last).
// Block = (b, h, 64-px half). Coalesced read (lane=w), LDS transpose,
// coalesced write (lane=c-pair, 128B/wave stores).
// ---------------------------------------------------------------------------
__global__ __launch_bounds__(256) void transpose_x(
        const float* __restrict__ x, unsigned short* __restrict__ xt) {
    __shared__ float s[64][65];
    int gid  = blockIdx.x;               // 4*128*2 = 1024
    int half = gid & 1;
    int h    = (gid >> 1) & 127;
    int b    = gid >> 8;
    int w0   = half * 64;
    int t    = threadIdx.x;
    int w = t & 63, cg = t >> 6;

    const float* xb = x + (size_t)b * CINc * HW + (size_t)h * Wn + w0 + w;
    #pragma unroll
    for (int i = 0; i < 16; ++i) {
        int c = cg * 16 + i;
        s[c][w] = xb[(size_t)c * HW];
    }
    __syncthreads();

    int cpair = t & 31, pxg = t >> 5;
    unsigned* xtp = (unsigned*)xt;
    #pragma unroll
    for (int i = 0; i < 8; ++i) {
        int px = pxg * 8 + i;
        float v0 = s[cpair * 2][px], v1 = s[cpair * 2 + 1][px];
        unsigned d = (unsigned)f2bf(v0) | ((unsigned)f2bf(v1) << 16);
        xtp[(((size_t)(b * Hn + h) * Wn) + w0 + px) * 32 + cpair] = d;
    }
}

// ---------------------------------------------------------------------------
// prep: wkb[k][o][c] bf16 <- w_def[o][c][k] ; wob[t][m(32,pad)][c] bf16 <- w_off
// ---------------------------------------------------------------------------
__global__ void prep_weights(const float* __restrict__ w_off,
                             const float* __restrict__ w_def,
                             unsigned short* __restrict__ wkb,
                             unsigned short* __restrict__ wob) {
    int idx = blockIdx.x * 256 + threadIdx.x;
    if (idx < COUTc * CINc * KKc) {                 // 36864
        int k = idx % 9;
        int c = (idx / 9) % 64;
        int o = idx / 576;
        wkb[((size_t)k * 64 + o) * 64 + c] = f2bf(w_def[idx]);
    }
    int j = idx - COUTc * CINc * KKc;
    if (j >= 0 && j < KKc * 32 * CINc) {            // 18432: wob[t<<11|m<<6|c]
        int c = j & 63, m = (j >> 6) & 31, t = j >> 11;
        unsigned short v = 0;
        if (m < NOFF) v = f2bf(w_off[((size_t)m * 64 + c) * 9 + t]);
        wob[j] = v;
    }
}

// ---------------------------------------------------------------------------
// offset conv v5: pure MFMA, zero LDS, zero barriers. Block = (b,h,half),
// 1024 blocks, XCD-swizzled. Wave owns a 16-px strip; per tap (ty,tx):
// B-frag = ONE 16B load from xt (8 channels of the tap pixel), x-boundary
// handled by &mask, y-boundary by uniform skip. A-frags L1-hot from wob.
// ---------------------------------------------------------------------------
__global__ __launch_bounds__(256, 4) void offset_conv_v5(
        const unsigned short* __restrict__ xt,
        const unsigned short* __restrict__ wob,
        const float* __restrict__ b_off, float* __restrict__ off) {
    int gid  = blockIdx.x;               // 1024
    int xcd  = gid & 7;
    int j    = gid >> 3;
    int half = j & 1;
    int hh   = (j >> 1) & 15;
    int b    = (j >> 5) & 3;
    int h    = xcd * 16 + hh;
    int w0   = half * 64;
    int tid  = threadIdx.x;
    int lane = tid & 63;
    int wave = __builtin_amdgcn_readfirstlane(tid >> 6);
    int l15  = lane & 15, quad = lane >> 4;
    int p    = w0 + wave * 16 + l15;     // this lane's pixel col

    f32x4 oa0 = (f32x4){0.f, 0.f, 0.f, 0.f};
    f32x4 oa1 = (f32x4){0.f, 0.f, 0.f, 0.f};

    #pragma unroll
    for (int t9 = 0; t9 < 9; ++t9) {
        int ty = t9 / 3, tx = t9 % 3;
        int y = h - 1 + ty;
        if (y < 0 || y >= Hn) continue;          // wave-uniform skip
        int xg = p - 1 + tx;
        unsigned msk = (xg >= 0 && xg < Wn) ? 0xFFFFFFFFu : 0u;
        int xc = min(max(xg, 0), Wn - 1);
        size_t base = (((size_t)b * Hn + y) * Wn + xc) * 64;
        #pragma unroll
        for (int kc = 0; kc < 2; ++kc) {
            union { bf16x8 v; uint4 u; } bf;
            bf.u = *(const uint4*)(xt + base + kc * 32 + quad * 8);
            bf.u.x &= msk; bf.u.y &= msk; bf.u.z &= msk; bf.u.w &= msk;
            bf16x8 a0 = *(const bf16x8*)(wob + ((t9 * 32 + l15) * 64 + kc * 32 + quad * 8));
            bf16x8 a1 = *(const bf16x8*)(wob + ((t9 * 32 + 16 + l15) * 64 + kc * 32 + quad * 8));
            oa0 = __builtin_amdgcn_mfma_f32_16x16x32_bf16(a0, bf.v, oa0, 0, 0, 0);
            oa1 = __builtin_amdgcn_mfma_f32_16x16x32_bf16(a1, bf.v, oa1, 0, 0, 0);
        }
    }

    // C layout: col=l15 (=pixel), row=quad*4+r (=oc)
    #pragma unroll
    for (int r = 0; r < 4; ++r) {
        int oc = quad * 4 + r;
        off[(((size_t)b * NOFF + oc) * Hn + h) * Wn + p] = oa0[r] + b_off[oc];
    }
    if (quad == 0) {
        #pragma unroll
        for (int r = 0; r < 2; ++r) {
            int oc = 16 + r;
            off[(((size_t)b * NOFF + oc) * Hn + h) * Wn + p] = oa1[r] + b_off[oc];
        }
    }
}

// ---------------------------------------------------------------------------
// deform main v5: phase-1 (folded clip weights, from v4) + barrier-free main
// loop: per k, 4 corner loads x 2 kc of 16B each from channel-last xt ->
// fp32 blend -> bf16 B-frag in registers -> 8 MFMA. No s_st LDS round-trip,
// no per-k barriers, no bank conflicts; compiler pipelines across k.
// ---------------------------------------------------------------------------
__global__ __launch_bounds__(256, 4) void deform_main_v5(
        const unsigned short* __restrict__ xt, const float* __restrict__ off,
        const unsigned short* __restrict__ wkb, float* __restrict__ out) {
    __shared__ unsigned s_ad[KKc][64][2];   // {atop, abot} elem offsets
    __shared__ __half2  s_wh[KKc][64][2];   // folded corner weights (fp16)

    int gid  = blockIdx.x;                  // 1024
    int xcd  = gid & 7;
    int j    = gid >> 3;
    int half = j & 1;
    int hh   = (j >> 1) & 15;
    int b    = (j >> 5) & 3;
    int h    = xcd * 16 + hh;
    int w0   = half * 64;
    int tid  = threadIdx.x;
    int lane = tid & 63;
    int wave = __builtin_amdgcn_readfirstlane(tid >> 6);
    int l15  = lane & 15;
    int quad = lane >> 4;

    // ---- phase 1: 9*64 (k,p) items, 256 threads ----
    for (int jj = tid; jj < KKc * 64; jj += 256) {
        int k = jj >> 6, pp = jj & 63;
        float dy = off[(((size_t)b * NOFF + 2 * k) * Hn + h) * Wn + w0 + pp];
        float dx = off[(((size_t)b * NOFF + 2 * k + 1) * Hn + h) * Wn + w0 + pp];
        float py = (float)(h - 1 + k / 3) + dy;
        float px = (float)(w0 + pp - 1 + k % 3) + dx;
        float y0f = floorf(py), x0f = floorf(px);
        float fy = py - y0f, fx = px - x0f;
        int y0 = (int)y0f, x0 = (int)x0f;
        bool vy0 = (y0 >= 0) & (y0 < Hn);
        bool vy1 = (y0 + 1 >= 0) & (y0 + 1 < Hn);
        bool vx0 = (x0 >= 0) & (x0 < Wn);
        bool vx1 = (x0 + 1 >= 0) & (x0 + 1 < Wn);
        float wy0 = vy0 ? 1.f - fy : 0.f;
        float wy1 = vy1 ? fy : 0.f;
        float wx0 = vx0 ? 1.f - fx : 0.f;
        float wx1 = vx1 ? fx : 0.f;
        int xc = min(max(x0, 0), Wn - 2);               // pair base
        bool sel0 = (min(max(x0, 0), Wn - 1) != xc);
        bool sel1 = ((min(max(x0 + 1, 0), Wn - 1) - xc) == 1);
        float Wa = (sel0 ? 0.f : wx0) + (sel1 ? 0.f : wx1);
        float Wb = (sel0 ? wx0 : 0.f) + (sel1 ? wx1 : 0.f);
        int yc0 = min(max(y0, 0), Hn - 1), yc1 = min(max(y0 + 1, 0), Hn - 1);
        s_ad[k][pp][0] = (unsigned)((yc0 * Wn + xc) * 64);
        s_ad[k][pp][1] = (unsigned)((yc1 * Wn + xc) * 64);
        s_wh[k][pp][0] = __floats2half2_rn(wy0 * Wa, wy0 * Wb);
        s_wh[k][pp][1] = __floats2half2_rn(wy1 * Wa, wy1 * Wb);
    }
    __syncthreads();

    f32x4 acc[4];
    #pragma unroll
    for (int ot = 0; ot < 4; ++ot) acc[ot] = (f32x4){0.f, 0.f, 0.f, 0.f};

    int pi = wave * 16 + l15;               // this lane's block-pixel
    const unsigned short* xtb = xt + (size_t)b * HW * 64;

    for (int k = 0; k < KKc; ++k) {
        unsigned atop = s_ad[k][pi][0];     // broadcast (4 quads same addr)
        unsigned abot = s_ad[k][pi][1];
        __half2 w01 = s_wh[k][pi][0], w23 = s_wh[k][pi][1];
        float W0 = __low2float(w01), W1 = __high2float(w01);
        float W2 = __low2float(w23), W3 = __high2float(w23);

        #pragma unroll
        for (int kc = 0; kc < 2; ++kc) {
            int co = kc * 32 + quad * 8;
            union { uint4 q; unsigned d[4]; } t0, t1, b0, b1;
            t0.q = *(const uint4*)(xtb + atop + co);        // (yc0, xc)
            t1.q = *(const uint4*)(xtb + atop + 64 + co);   // (yc0, xc+1)
            b0.q = *(const uint4*)(xtb + abot + co);        // (yc1, xc)
            b1.q = *(const uint4*)(xtb + abot + 64 + co);   // (yc1, xc+1)

            union { bf16x8 v; unsigned u[4]; } bf;
            #pragma unroll
            for (int jd = 0; jd < 4; ++jd) {
                float t0l = __uint_as_float(t0.d[jd] << 16);
                float t0h = __uint_as_float(t0.d[jd] & 0xFFFF0000u);
                float t1l = __uint_as_float(t1.d[jd] << 16);
                float t1h = __uint_as_float(t1.d[jd] & 0xFFFF0000u);
                float b0l = __uint_as_float(b0.d[jd] << 16);
                float b0h = __uint_as_float(b0.d[jd] & 0xFFFF0000u);
                float b1l = __uint_as_float(b1.d[jd] << 16);
                float b1h = __uint_as_float(b1.d[jd] & 0xFFFF0000u);
                float vl = W0 * t0l + W1 * t1l + W2 * b0l + W3 * b1l;
                float vh = W0 * t0h + W1 * t1h + W2 * b0h + W3 * b1h;
                bf.u[jd] = (unsigned)f2bf(vl) | ((unsigned)f2bf(vh) << 16);
            }
            #pragma unroll
            for (int ot = 0; ot < 4; ++ot) {
                bf16x8 af = *(const bf16x8*)(wkb +
                    (((size_t)k * 64 + ot * 16 + l15) * 64 + kc * 32 + quad * 8));
                acc[ot] = __builtin_amdgcn_mfma_f32_16x16x32_bf16(af, bf.v, acc[ot], 0, 0, 0);
            }
        }
    }

    // ---- epilogue: C layout col=l15 (=pixel), row=quad*4+r ----
    #pragma unroll
    for (int ot = 0; ot < 4; ++ot)
        #pragma unroll
        for (int r = 0; r < 4; ++r) {
            int o = ot * 16 + quad * 4 + r;
            int p = w0 + wave * 16 + l15;
            out[(((size_t)b * COUTc + o) * Hn + h) * Wn + p] = acc[ot][r];
        }
}

// ---------------------------------------------------------------------------
extern "C" void kernel_launch(void* const* d_in, const int* in_sizes, int n_in,
                              void* d_out, int out_size, void* d_ws, size_t ws_size,
                              hipStream_t stream) {
    const float* x     = (const float*)d_in[0];
    const float* w_off = (const float*)d_in[1];
    const float* b_off = (const float*)d_in[2];
    const float* w_def = (const float*)d_in[3];
    float* out = (float*)d_out;

    char* ws = (char*)d_ws;
    unsigned short* xt = (unsigned short*)ws;                 // 8.39 MB, 16B-aligned
    ws += (size_t)Bn * HW * CINc * sizeof(unsigned short);
    float* off = (float*)ws;                                  // 4.72 MB
    ws += (size_t)Bn * NOFF * Hn * Wn * sizeof(float);
    unsigned short* wkb = (unsigned short*)ws;                // 73728 B
    ws += (size_t)KKc * COUTc * CINc * sizeof(unsigned short);
    unsigned short* wob = (unsigned short*)ws;                // 36864 B

    transpose_x<<<Bn * Hn * (Wn / 64), 256, 0, stream>>>(x, xt);
    prep_weights<<<216, 256, 0, stream>>>(w_off, w_def, wkb, wob);
    offset_conv_v5<<<Bn * Hn * (Wn / 64), 256, 0, stream>>>(xt, wob, b_off, off);
    deform_main_v5<<<Bn * Hn * (Wn / 64), 256, 0, stream>>>(xt, off, wkb, out);
}

// Round 7
// 123.899 us; speedup vs baseline: 1.6575x; 1.3363x over previous
//
#include <hip/hip_runtime.h>
#include <hip/hip_fp16.h>

#define Bn   4
#define CINc 64
#define COUTc 64
#define Hn   128
#define Wn   128
#define HW   (Hn * Wn)
#define KKc  9
#define NOFF 18

typedef short bf16x8 __attribute__((ext_vector_type(8)));
typedef float f32x4  __attribute__((ext_vector_type(4)));

__device__ inline unsigned short f2bf(float f) {   // RNE fp32 -> bf16
    unsigned int u = __float_as_uint(f);
    return (unsigned short)((u + 0x7fffu + ((u >> 16) & 1u)) >> 16);
}

// ---------------------------------------------------------------------------
// transpose_x: x[b][c][h][w] f32  ->  xt[b][h][w][c] bf16  (channel-last).
// ---------------------------------------------------------------------------
__global__ __launch_bounds__(256) void transpose_x(
        const float* __restrict__ x, unsigned short* __restrict__ xt) {
    __shared__ float s[64][65];
    int gid  = blockIdx.x;               // 4*128*2 = 1024
    int half = gid & 1;
    int h    = (gid >> 1) & 127;
    int b    = gid >> 8;
    int w0   = half * 64;
    int t    = threadIdx.x;
    int w = t & 63, cg = t >> 6;

    const float* xb = x + (size_t)b * CINc * HW + (size_t)h * Wn + w0 + w;
    #pragma unroll
    for (int i = 0; i < 16; ++i) {
        int c = cg * 16 + i;
        s[c][w] = xb[(size_t)c * HW];
    }
    __syncthreads();

    int cpair = t & 31, pxg = t >> 5;
    unsigned* xtp = (unsigned*)xt;
    #pragma unroll
    for (int i = 0; i < 8; ++i) {
        int px = pxg * 8 + i;
        float v0 = s[cpair * 2][px], v1 = s[cpair * 2 + 1][px];
        unsigned d = (unsigned)f2bf(v0) | ((unsigned)f2bf(v1) << 16);
        xtp[(((size_t)(b * Hn + h) * Wn) + w0 + px) * 32 + cpair] = d;
    }
}

// ---------------------------------------------------------------------------
// prep: lane-order swizzled weight layouts for direct LDS fragment reads.
// wkb_sw[seg=(k*2+kc)*4+ot][lane=quad*16+l15][j] = w_def[ot*16+l15][kc*32+quad*8+j][k]
// wob_sw[seg=(t*2+kc)*2+mt][lane][j]             = w_off[mt*16+l15][kc*32+quad*8+j][t] (m>=18 -> 0)
// ---------------------------------------------------------------------------
__global__ void prep_weights(const float* __restrict__ w_off,
                             const float* __restrict__ w_def,
                             unsigned short* __restrict__ wkb_sw,
                             unsigned short* __restrict__ wob_sw) {
    int idx = blockIdx.x * 256 + threadIdx.x;
    if (idx < 36864) {
        int j = idx & 7, l = (idx >> 3) & 63, s = idx >> 9;
        int k = s >> 3, kc = (s >> 2) & 1, ot = s & 3;
        int l15 = l & 15, quad = l >> 4;
        int o = ot * 16 + l15, c = kc * 32 + quad * 8 + j;
        wkb_sw[idx] = f2bf(w_def[((size_t)o * 64 + c) * 9 + k]);
    }
    int i2 = idx - 36864;
    if (i2 >= 0 && i2 < 18432) {
        int j = i2 & 7, l = (i2 >> 3) & 63, s = i2 >> 9;
        int t = s >> 2, kc = (s >> 1) & 1, mt = s & 1;
        int l15 = l & 15, quad = l >> 4;
        int m = mt * 16 + l15, c = kc * 32 + quad * 8 + j;
        unsigned short v = 0;
        if (m < NOFF) v = f2bf(w_off[((size_t)m * 64 + c) * 9 + t]);
        wob_sw[i2] = v;
    }
}

// ---------------------------------------------------------------------------
// offset conv v6: MFMA, A-frags from LDS (wob_sw staged once, lane-order ->
// ds_read_b128 at bank-floor rate, zero L2 re-reads). B-frag = one 16B
// coalesced load from channel-last xt. 4 blocks/CU.
// ---------------------------------------------------------------------------
__global__ __launch_bounds__(256, 4) void offset_conv_v6(
        const unsigned short* __restrict__ xt,
        const unsigned short* __restrict__ wob_sw,
        const float* __restrict__ b_off, float* __restrict__ off) {
    __shared__ bf16x8 s_w[36 * 64];      // 36864 B

    int gid  = blockIdx.x;               // 1024
    int xcd  = gid & 7;
    int j    = gid >> 3;
    int half = j & 1;
    int hh   = (j >> 1) & 15;
    int b    = (j >> 5) & 3;
    int h    = xcd * 16 + hh;
    int w0   = half * 64;
    int tid  = threadIdx.x;
    int lane = tid & 63;
    int wave = __builtin_amdgcn_readfirstlane(tid >> 6);
    int l15  = lane & 15, quad = lane >> 4;
    int p    = w0 + wave * 16 + l15;     // this lane's pixel col

    #pragma unroll
    for (int i = 0; i < 9; ++i) {        // 2304 uint4 total
        int e = tid + i * 256;
        ((uint4*)s_w)[e] = ((const uint4*)wob_sw)[e];
    }
    __syncthreads();

    f32x4 oa0 = (f32x4){0.f, 0.f, 0.f, 0.f};
    f32x4 oa1 = (f32x4){0.f, 0.f, 0.f, 0.f};

    #pragma unroll
    for (int t9 = 0; t9 < 9; ++t9) {
        int ty = t9 / 3, tx = t9 % 3;
        int y = h - 1 + ty;
        if (y < 0 || y >= Hn) continue;          // wave-uniform skip
        int xg = p - 1 + tx;
        unsigned msk = (xg >= 0 && xg < Wn) ? 0xFFFFFFFFu : 0u;
        int xc = min(max(xg, 0), Wn - 1);
        size_t base = (((size_t)b * Hn + y) * Wn + xc) * 64;
        #pragma unroll
        for (int kc = 0; kc < 2; ++kc) {
            union { bf16x8 v; uint4 u; } bf;
            bf.u = *(const uint4*)(xt + base + kc * 32 + quad * 8);
            bf.u.x &= msk; bf.u.y &= msk; bf.u.z &= msk; bf.u.w &= msk;
            bf16x8 a0 = s_w[((t9 * 2 + kc) * 2 + 0) * 64 + lane];
            bf16x8 a1 = s_w[((t9 * 2 + kc) * 2 + 1) * 64 + lane];
            oa0 = __builtin_amdgcn_mfma_f32_16x16x32_bf16(a0, bf.v, oa0, 0, 0, 0);
            oa1 = __builtin_amdgcn_mfma_f32_16x16x32_bf16(a1, bf.v, oa1, 0, 0, 0);
        }
    }

    #pragma unroll
    for (int r = 0; r < 4; ++r) {
        int oc = quad * 4 + r;
        off[(((size_t)b * NOFF + oc) * Hn + h) * Wn + p] = oa0[r] + b_off[oc];
    }
    if (quad == 0) {
        #pragma unroll
        for (int r = 0; r < 2; ++r) {
            int oc = 16 + r;
            off[(((size_t)b * NOFF + oc) * Hn + h) * Wn + p] = oa1[r] + b_off[oc];
        }
    }
}

// ---------------------------------------------------------------------------
// deform main v6: barrier-free gather loop; A-frags from LDS-resident
// swizzled wkb (one ds_read_b128 each, zero L2 traffic — kills the 295 MB/
// launch weight re-read that thrashed L1). 2 blocks/CU (80.6 KB LDS).
// ---------------------------------------------------------------------------
__global__ __launch_bounds__(256, 2) void deform_main_v6(
        const unsigned short* __restrict__ xt, const float* __restrict__ off,
        const unsigned short* __restrict__ wkb_sw, float* __restrict__ out) {
    __shared__ bf16x8   s_w[72 * 64];       // 73728 B
    __shared__ unsigned s_ad[KKc][64];      // yc0 | yc1<<8 | xc<<16
    __shared__ __half2  s_wh[KKc][64][2];   // folded corner weights

    int gid  = blockIdx.x;                  // 1024
    int xcd  = gid & 7;
    int j    = gid >> 3;
    int half = j & 1;
    int hh   = (j >> 1) & 15;
    int b    = (j >> 5) & 3;
    int h    = xcd * 16 + hh;
    int w0   = half * 64;
    int tid  = threadIdx.x;
    int lane = tid & 63;
    int wave = __builtin_amdgcn_readfirstlane(tid >> 6);
    int l15  = lane & 15;
    int quad = lane >> 4;

    #pragma unroll
    for (int i = 0; i < 18; ++i) {          // 4608 uint4 total
        int e = tid + i * 256;
        ((uint4*)s_w)[e] = ((const uint4*)wkb_sw)[e];
    }

    // ---- phase 1 (independent of staging; one barrier covers both) ----
    for (int jj = tid; jj < KKc * 64; jj += 256) {
        int k = jj >> 6, pp = jj & 63;
        float dy = off[(((size_t)b * NOFF + 2 * k) * Hn + h) * Wn + w0 + pp];
        float dx = off[(((size_t)b * NOFF + 2 * k + 1) * Hn + h) * Wn + w0 + pp];
        float py = (float)(h - 1 + k / 3) + dy;
        float px = (float)(w0 + pp - 1 + k % 3) + dx;
        float y0f = floorf(py), x0f = floorf(px);
        float fy = py - y0f, fx = px - x0f;
        int y0 = (int)y0f, x0 = (int)x0f;
        bool vy0 = (y0 >= 0) & (y0 < Hn);
        bool vy1 = (y0 + 1 >= 0) & (y0 + 1 < Hn);
        bool vx0 = (x0 >= 0) & (x0 < Wn);
        bool vx1 = (x0 + 1 >= 0) & (x0 + 1 < Wn);
        float wy0 = vy0 ? 1.f - fy : 0.f;
        float wy1 = vy1 ? fy : 0.f;
        float wx0 = vx0 ? 1.f - fx : 0.f;
        float wx1 = vx1 ? fx : 0.f;
        int xc = min(max(x0, 0), Wn - 2);               // pair base
        bool sel0 = (min(max(x0, 0), Wn - 1) != xc);
        bool sel1 = ((min(max(x0 + 1, 0), Wn - 1) - xc) == 1);
        float Wa = (sel0 ? 0.f : wx0) + (sel1 ? 0.f : wx1);
        float Wb = (sel0 ? wx0 : 0.f) + (sel1 ? wx1 : 0.f);
        int yc0 = min(max(y0, 0), Hn - 1), yc1 = min(max(y0 + 1, 0), Hn - 1);
        s_ad[k][pp] = (unsigned)yc0 | ((unsigned)yc1 << 8) | ((unsigned)xc << 16);
        s_wh[k][pp][0] = __floats2half2_rn(wy0 * Wa, wy0 * Wb);
        s_wh[k][pp][1] = __floats2half2_rn(wy1 * Wa, wy1 * Wb);
    }
    __syncthreads();

    f32x4 acc[4];
    #pragma unroll
    for (int ot = 0; ot < 4; ++ot) acc[ot] = (f32x4){0.f, 0.f, 0.f, 0.f};

    int pi = wave * 16 + l15;               // this lane's block-pixel
    const unsigned short* xtb = xt + (size_t)b * HW * 64;

    #pragma unroll
    for (int k = 0; k < KKc; ++k) {
        unsigned ad = s_ad[k][pi];
        int xc = (int)(ad >> 16);
        unsigned atop = (unsigned)(((ad & 255u) * Wn + xc) * 64);
        unsigned abot = (unsigned)((((ad >> 8) & 255u) * Wn + xc) * 64);
        __half2 w01 = s_wh[k][pi][0], w23 = s_wh[k][pi][1];
        float W0 = __low2float(w01), W1 = __high2float(w01);
        float W2 = __low2float(w23), W3 = __high2float(w23);

        #pragma unroll
        for (int kc = 0; kc < 2; ++kc) {
            int co = kc * 32 + quad * 8;
            union { uint4 q; unsigned d[4]; } t0, t1, b0, b1;
            t0.q = *(const uint4*)(xtb + atop + co);        // (yc0, xc)
            t1.q = *(const uint4*)(xtb + atop + 64 + co);   // (yc0, xc+1)
            b0.q = *(const uint4*)(xtb + abot + co);        // (yc1, xc)
            b1.q = *(const uint4*)(xtb + abot + 64 + co);   // (yc1, xc+1)

            union { bf16x8 v; unsigned u[4]; } bf;
            #pragma unroll
            for (int jd = 0; jd < 4; ++jd) {
                float t0l = __uint_as_float(t0.d[jd] << 16);
                float t0h = __uint_as_float(t0.d[jd] & 0xFFFF0000u);
                float t1l = __uint_as_float(t1.d[jd] << 16);
                float t1h = __uint_as_float(t1.d[jd] & 0xFFFF0000u);
                float b0l = __uint_as_float(b0.d[jd] << 16);
                float b0h = __uint_as_float(b0.d[jd] & 0xFFFF0000u);
                float b1l = __uint_as_float(b1.d[jd] << 16);
                float b1h = __uint_as_float(b1.d[jd] & 0xFFFF0000u);
                float vl = W0 * t0l + W1 * t1l + W2 * b0l + W3 * b1l;
                float vh = W0 * t0h + W1 * t1h + W2 * b1h + W3 * b1h;
                // NOTE: vh must use b0h for W2 term — keep exact v5 form:
                vh = W0 * t0h + W1 * t1h + W2 * b0h + W3 * b1h;
                bf.u[jd] = (unsigned)f2bf(vl) | ((unsigned)f2bf(vh) << 16);
            }
            #pragma unroll
            for (int ot = 0; ot < 4; ++ot) {
                bf16x8 af = s_w[((k * 2 + kc) * 4 + ot) * 64 + lane];
                acc[ot] = __builtin_amdgcn_mfma_f32_16x16x32_bf16(af, bf.v, acc[ot], 0, 0, 0);
            }
        }
    }

    #pragma unroll
    for (int ot = 0; ot < 4; ++ot)
        #pragma unroll
        for (int r = 0; r < 4; ++r) {
            int o = ot * 16 + quad * 4 + r;
            int p = w0 + wave * 16 + l15;
            out[(((size_t)b * COUTc + o) * Hn + h) * Wn + p] = acc[ot][r];
        }
}

// ---------------------------------------------------------------------------
extern "C" void kernel_launch(void* const* d_in, const int* in_sizes, int n_in,
                              void* d_out, int out_size, void* d_ws, size_t ws_size,
                              hipStream_t stream) {
    const float* x     = (const float*)d_in[0];
    const float* w_off = (const float*)d_in[1];
    const float* b_off = (const float*)d_in[2];
    const float* w_def = (const float*)d_in[3];
    float* out = (float*)d_out;

    char* ws = (char*)d_ws;
    unsigned short* xt = (unsigned short*)ws;                 // 8.39 MB
    ws += (size_t)Bn * HW * CINc * sizeof(unsigned short);
    float* off = (float*)ws;                                  // 4.72 MB
    ws += (size_t)Bn * NOFF * Hn * Wn * sizeof(float);
    unsigned short* wkb_sw = (unsigned short*)ws;             // 73728 B
    ws += 36864 * sizeof(unsigned short);
    unsigned short* wob_sw = (unsigned short*)ws;             // 36864 B

    transpose_x<<<Bn * Hn * (Wn / 64), 256, 0, stream>>>(x, xt);
    prep_weights<<<216, 256, 0, stream>>>(w_off, w_def, wkb_sw, wob_sw);
    offset_conv_v6<<<Bn * Hn * (Wn / 64), 256, 0, stream>>>(xt, wob_sw, b_off, off);
    deform_main_v6<<<Bn * Hn * (Wn / 64), 256, 0, stream>>>(xt, off, wkb_sw, out);
}

// Round 8
// 122.777 us; speedup vs baseline: 1.6727x; 1.0091x over previous
//
#include <hip/hip_runtime.h>
#include <hip/hip_fp16.h>

#define Bn   4
#define CINc 64
#define COUTc 64
#define Hn   128
#define Wn   128
#define HW   (Hn * Wn)
#define KKc  9
#define NOFF 18

typedef short bf16x8 __attribute__((ext_vector_type(8)));
typedef float f32x4  __attribute__((ext_vector_type(4)));

__device__ inline unsigned short f2bf(float f) {   // RNE fp32 -> bf16
    unsigned int u = __float_as_uint(f);
    return (unsigned short)((u + 0x7fffu + ((u >> 16) & 1u)) >> 16);
}

// ---------------------------------------------------------------------------
// prep_all: blocks 0..1023 transpose x -> channel-last bf16 xt;
// blocks 1024..1239 build lane-order swizzled weight tables.
//   wkb_sw[seg=(k*2+kc)*4+ot][lane][j] = w_def[ot*16+l15][kc*32+quad*8+j][k]
//   wob_sw[seg=(t*2+kc)*2+mt][lane][j] = w_off[mt*16+l15][kc*32+quad*8+j][t]
// ---------------------------------------------------------------------------
__global__ __launch_bounds__(256) void prep_all(
        const float* __restrict__ x, unsigned short* __restrict__ xt,
        const float* __restrict__ w_off, const float* __restrict__ w_def,
        unsigned short* __restrict__ wkb_sw, unsigned short* __restrict__ wob_sw) {
    int gb = blockIdx.x;
    int t  = threadIdx.x;
    if (gb < 1024) {
        __shared__ float s[64][65];
        int half = gb & 1;
        int h    = (gb >> 1) & 127;
        int b    = gb >> 8;
        int w0   = half * 64;
        int w = t & 63, cg = t >> 6;

        const float* xb = x + (size_t)b * CINc * HW + (size_t)h * Wn + w0 + w;
        #pragma unroll
        for (int i = 0; i < 16; ++i) {
            int c = cg * 16 + i;
            s[c][w] = xb[(size_t)c * HW];
        }
        __syncthreads();

        int cpair = t & 31, pxg = t >> 5;
        unsigned* xtp = (unsigned*)xt;
        #pragma unroll
        for (int i = 0; i < 8; ++i) {
            int px = pxg * 8 + i;
            float v0 = s[cpair * 2][px], v1 = s[cpair * 2 + 1][px];
            unsigned d = (unsigned)f2bf(v0) | ((unsigned)f2bf(v1) << 16);
            xtp[(((size_t)(b * Hn + h) * Wn) + w0 + px) * 32 + cpair] = d;
        }
        return;
    }
    int idx = (gb - 1024) * 256 + t;
    if (idx < 36864) {
        int j = idx & 7, l = (idx >> 3) & 63, s = idx >> 9;
        int k = s >> 3, kc = (s >> 2) & 1, ot = s & 3;
        int l15 = l & 15, quad = l >> 4;
        int o = ot * 16 + l15, c = kc * 32 + quad * 8 + j;
        wkb_sw[idx] = f2bf(w_def[((size_t)o * 64 + c) * 9 + k]);
    }
    int i2 = idx - 36864;
    if (i2 >= 0 && i2 < 18432) {
        int j = i2 & 7, l = (i2 >> 3) & 63, s = i2 >> 9;
        int tt = s >> 2, kc = (s >> 1) & 1, mt = s & 1;
        int l15 = l & 15, quad = l >> 4;
        int m = mt * 16 + l15, c = kc * 32 + quad * 8 + j;
        unsigned short v = 0;
        if (m < NOFF) v = f2bf(w_off[((size_t)m * 64 + c) * 9 + tt]);
        wob_sw[i2] = v;
    }
}

// ---------------------------------------------------------------------------
// offset conv v7: all 18 tap loads prefetched before the MFMA chain
// (uniform control flow; y-validity folded into the per-lane mask).
// A-frags from LDS-resident lane-order wob_sw.
// ---------------------------------------------------------------------------
__global__ __launch_bounds__(256, 4) void offset_conv_v7(
        const unsigned short* __restrict__ xt,
        const unsigned short* __restrict__ wob_sw,
        const float* __restrict__ b_off, float* __restrict__ off) {
    __shared__ bf16x8 s_w[36 * 64];      // 36864 B

    int gid  = blockIdx.x;               // 1024
    int xcd  = gid & 7;
    int j    = gid >> 3;
    int half = j & 1;
    int hh   = (j >> 1) & 15;
    int b    = (j >> 5) & 3;
    int h    = xcd * 16 + hh;
    int w0   = half * 64;
    int tid  = threadIdx.x;
    int lane = tid & 63;
    int wave = __builtin_amdgcn_readfirstlane(tid >> 6);
    int l15  = lane & 15, quad = lane >> 4;
    int p    = w0 + wave * 16 + l15;     // this lane's pixel col

    #pragma unroll
    for (int i = 0; i < 9; ++i) {        // 2304 uint4 total
        int e = tid + i * 256;
        ((uint4*)s_w)[e] = ((const uint4*)wob_sw)[e];
    }

    // ---- prefetch all 18 tap fragments ----
    uint4 L[9][2];
    unsigned msk[9];
    #pragma unroll
    for (int t9 = 0; t9 < 9; ++t9) {
        int ty = t9 / 3, tx = t9 % 3;
        int y  = h - 1 + ty;
        int xg = p - 1 + tx;
        bool v = (y >= 0) && (y < Hn) && (xg >= 0) && (xg < Wn);
        msk[t9] = v ? 0xFFFFFFFFu : 0u;
        int yc = min(max(y, 0), Hn - 1);
        int xc = min(max(xg, 0), Wn - 1);
        size_t base = (((size_t)b * Hn + yc) * Wn + xc) * 64;
        L[t9][0] = *(const uint4*)(xt + base + quad * 8);
        L[t9][1] = *(const uint4*)(xt + base + 32 + quad * 8);
    }
    __syncthreads();

    f32x4 oa0 = (f32x4){0.f, 0.f, 0.f, 0.f};
    f32x4 oa1 = (f32x4){0.f, 0.f, 0.f, 0.f};

    #pragma unroll
    for (int t9 = 0; t9 < 9; ++t9) {
        unsigned m = msk[t9];
        #pragma unroll
        for (int kc = 0; kc < 2; ++kc) {
            union { bf16x8 v; uint4 u; } bf;
            bf.u = L[t9][kc];
            bf.u.x &= m; bf.u.y &= m; bf.u.z &= m; bf.u.w &= m;
            bf16x8 a0 = s_w[((t9 * 2 + kc) * 2 + 0) * 64 + lane];
            bf16x8 a1 = s_w[((t9 * 2 + kc) * 2 + 1) * 64 + lane];
            oa0 = __builtin_amdgcn_mfma_f32_16x16x32_bf16(a0, bf.v, oa0, 0, 0, 0);
            oa1 = __builtin_amdgcn_mfma_f32_16x16x32_bf16(a1, bf.v, oa1, 0, 0, 0);
        }
    }

    #pragma unroll
    for (int r = 0; r < 4; ++r) {
        int oc = quad * 4 + r;
        off[(((size_t)b * NOFF + oc) * Hn + h) * Wn + p] = oa0[r] + b_off[oc];
    }
    if (quad == 0) {
        #pragma unroll
        for (int r = 0; r < 2; ++r) {
            int oc = 16 + r;
            off[(((size_t)b * NOFF + oc) * Hn + h) * Wn + p] = oa1[r] + b_off[oc];
        }
    }
}

// ---------------------------------------------------------------------------
// deform main v7: software-pipelined gather. Per-lane addr/weights for all
// 9 k's preloaded to registers after the single barrier; corner loads of
// k+1 issued into the alternate register set before blending/MFMA-ing k.
// A-frags from LDS-resident lane-order wkb_sw.
// ---------------------------------------------------------------------------
__global__ __launch_bounds__(256, 2) void deform_main_v7(
        const unsigned short* __restrict__ xt, const float* __restrict__ off,
        const unsigned short* __restrict__ wkb_sw, float* __restrict__ out) {
    __shared__ bf16x8   s_w[72 * 64];       // 73728 B
    __shared__ unsigned s_ad[KKc][64];      // yc0 | yc1<<8 | xc<<16
    __shared__ __half2  s_wh[KKc][64][2];   // folded corner weights

    int gid  = blockIdx.x;                  // 1024
    int xcd  = gid & 7;
    int j    = gid >> 3;
    int half = j & 1;
    int hh   = (j >> 1) & 15;
    int b    = (j >> 5) & 3;
    int h    = xcd * 16 + hh;
    int w0   = half * 64;
    int tid  = threadIdx.x;
    int lane = tid & 63;
    int wave = __builtin_amdgcn_readfirstlane(tid >> 6);
    int l15  = lane & 15;
    int quad = lane >> 4;

    #pragma unroll
    for (int i = 0; i < 18; ++i) {          // 4608 uint4 total
        int e = tid + i * 256;
        ((uint4*)s_w)[e] = ((const uint4*)wkb_sw)[e];
    }

    // ---- phase 1 (one barrier covers staging + phase-1) ----
    for (int jj = tid; jj < KKc * 64; jj += 256) {
        int k = jj >> 6, pp = jj & 63;
        float dy = off[(((size_t)b * NOFF + 2 * k) * Hn + h) * Wn + w0 + pp];
        float dx = off[(((size_t)b * NOFF + 2 * k + 1) * Hn + h) * Wn + w0 + pp];
        float py = (float)(h - 1 + k / 3) + dy;
        float px = (float)(w0 + pp - 1 + k % 3) + dx;
        float y0f = floorf(py), x0f = floorf(px);
        float fy = py - y0f, fx = px - x0f;
        int y0 = (int)y0f, x0 = (int)x0f;
        bool vy0 = (y0 >= 0) & (y0 < Hn);
        bool vy1 = (y0 + 1 >= 0) & (y0 + 1 < Hn);
        bool vx0 = (x0 >= 0) & (x0 < Wn);
        bool vx1 = (x0 + 1 >= 0) & (x0 + 1 < Wn);
        float wy0 = vy0 ? 1.f - fy : 0.f;
        float wy1 = vy1 ? fy : 0.f;
        float wx0 = vx0 ? 1.f - fx : 0.f;
        float wx1 = vx1 ? fx : 0.f;
        int xc = min(max(x0, 0), Wn - 2);               // pair base
        bool sel0 = (min(max(x0, 0), Wn - 1) != xc);
        bool sel1 = ((min(max(x0 + 1, 0), Wn - 1) - xc) == 1);
        float Wa = (sel0 ? 0.f : wx0) + (sel1 ? 0.f : wx1);
        float Wb = (sel0 ? wx0 : 0.f) + (sel1 ? wx1 : 0.f);
        int yc0 = min(max(y0, 0), Hn - 1), yc1 = min(max(y0 + 1, 0), Hn - 1);
        s_ad[k][pp] = (unsigned)yc0 | ((unsigned)yc1 << 8) | ((unsigned)xc << 16);
        s_wh[k][pp][0] = __floats2half2_rn(wy0 * Wa, wy0 * Wb);
        s_wh[k][pp][1] = __floats2half2_rn(wy1 * Wa, wy1 * Wb);
    }
    __syncthreads();

    int pi = wave * 16 + l15;               // this lane's block-pixel
    const unsigned short* xtb = xt + (size_t)b * HW * 64;

    // ---- preload per-lane addr/weights for all k to registers ----
    unsigned at[KKc], ab[KKc];
    float Wf[KKc][4];
    #pragma unroll
    for (int k = 0; k < KKc; ++k) {
        unsigned ad = s_ad[k][pi];
        int xc = (int)(ad >> 16);
        at[k] = (unsigned)(((ad & 255u) * Wn + xc) * 64);
        ab[k] = (unsigned)((((ad >> 8) & 255u) * Wn + xc) * 64);
        __half2 w01 = s_wh[k][pi][0], w23 = s_wh[k][pi][1];
        Wf[k][0] = __low2float(w01); Wf[k][1] = __high2float(w01);
        Wf[k][2] = __low2float(w23); Wf[k][3] = __high2float(w23);
    }

    f32x4 acc[4];
    #pragma unroll
    for (int ot = 0; ot < 4; ++ot) acc[ot] = (f32x4){0.f, 0.f, 0.f, 0.f};

    // ---- software-pipelined main loop ----
    uint4 R[2][8];                          // [stage][kc*4 + corner]
    int co0 = quad * 8, co1 = 32 + quad * 8;

    #define FETCH(kk, st)                                            \
        do {                                                         \
            R[st][0] = *(const uint4*)(xtb + at[kk] + co0);          \
            R[st][1] = *(const uint4*)(xtb + at[kk] + 64 + co0);     \
            R[st][2] = *(const uint4*)(xtb + ab[kk] + co0);          \
            R[st][3] = *(const uint4*)(xtb + ab[kk] + 64 + co0);     \
            R[st][4] = *(const uint4*)(xtb + at[kk] + co1);          \
            R[st][5] = *(const uint4*)(xtb + at[kk] + 64 + co1);     \
            R[st][6] = *(const uint4*)(xtb + ab[kk] + co1);          \
            R[st][7] = *(const uint4*)(xtb + ab[kk] + 64 + co1);     \
        } while (0)

    FETCH(0, 0);
    #pragma unroll
    for (int k = 0; k < KKc; ++k) {
        if (k < KKc - 1) FETCH(k + 1, (k + 1) & 1);
        const uint4* C = R[k & 1];
        float W0 = Wf[k][0], W1 = Wf[k][1], W2 = Wf[k][2], W3 = Wf[k][3];
        #pragma unroll
        for (int kc = 0; kc < 2; ++kc) {
            const unsigned* t0 = (const unsigned*)&C[kc * 4 + 0];
            const unsigned* t1 = (const unsigned*)&C[kc * 4 + 1];
            const unsigned* b0 = (const unsigned*)&C[kc * 4 + 2];
            const unsigned* b1 = (const unsigned*)&C[kc * 4 + 3];
            union { bf16x8 v; unsigned u[4]; } bf;
            #pragma unroll
            for (int jd = 0; jd < 4; ++jd) {
                float t0l = __uint_as_float(t0[jd] << 16);
                float t0h = __uint_as_float(t0[jd] & 0xFFFF0000u);
                float t1l = __uint_as_float(t1[jd] << 16);
                float t1h = __uint_as_float(t1[jd] & 0xFFFF0000u);
                float b0l = __uint_as_float(b0[jd] << 16);
                float b0h = __uint_as_float(b0[jd] & 0xFFFF0000u);
                float b1l = __uint_as_float(b1[jd] << 16);
                float b1h = __uint_as_float(b1[jd] & 0xFFFF0000u);
                float vl = W0 * t0l + W1 * t1l + W2 * b0l + W3 * b1l;
                float vh = W0 * t0h + W1 * t1h + W2 * b0h + W3 * b1h;
                bf.u[jd] = (unsigned)f2bf(vl) | ((unsigned)f2bf(vh) << 16);
            }
            #pragma unroll
            for (int ot = 0; ot < 4; ++ot) {
                bf16x8 af = s_w[((k * 2 + kc) * 4 + ot) * 64 + lane];
                acc[ot] = __builtin_amdgcn_mfma_f32_16x16x32_bf16(af, bf.v, acc[ot], 0, 0, 0);
            }
        }
    }
    #undef FETCH

    #pragma unroll
    for (int ot = 0; ot < 4; ++ot)
        #pragma unroll
        for (int r = 0; r < 4; ++r) {
            int o = ot * 16 + quad * 4 + r;
            int p = w0 + wave * 16 + l15;
            out[(((size_t)b * COUTc + o) * Hn + h) * Wn + p] = acc[ot][r];
        }
}

// ---------------------------------------------------------------------------
extern "C" void kernel_launch(void* const* d_in, const int* in_sizes, int n_in,
                              void* d_out, int out_size, void* d_ws, size_t ws_size,
                              hipStream_t stream) {
    const float* x     = (const float*)d_in[0];
    const float* w_off = (const float*)d_in[1];
    const float* b_off = (const float*)d_in[2];
    const float* w_def = (const float*)d_in[3];
    float* out = (float*)d_out;

    char* ws = (char*)d_ws;
    unsigned short* xt = (unsigned short*)ws;                 // 8.39 MB
    ws += (size_t)Bn * HW * CINc * sizeof(unsigned short);
    float* off = (float*)ws;                                  // 4.72 MB
    ws += (size_t)Bn * NOFF * Hn * Wn * sizeof(float);
    unsigned short* wkb_sw = (unsigned short*)ws;             // 73728 B
    ws += 36864 * sizeof(unsigned short);
    unsigned short* wob_sw = (unsigned short*)ws;             // 36864 B

    prep_all<<<1024 + 216, 256, 0, stream>>>(x, xt, w_off, w_def, wkb_sw, wob_sw);
    offset_conv_v7<<<Bn * Hn * (Wn / 64), 256, 0, stream>>>(xt, wob_sw, b_off, off);
    deform_main_v7<<<Bn * Hn * (Wn / 64), 256, 0, stream>>>(xt, off, wkb_sw, out);
}